// Round 1
// baseline (223.622 us; speedup 1.0000x reference)
//
#include <hip/hip_runtime.h>
#include <hip/hip_bf16.h>
#include <stdint.h>

#define B_N   16
#define C_N   256
#define W_N   64
#define HW_N  4096
#define CK_N  32      // f,g channels
#define CH_N  128     // h channels
#define HWP_N 1024    // pooled spatial
#define MR_N  192     // CK+CK+CH rows in fused conv weight

typedef __attribute__((ext_vector_type(8))) short short8;
typedef __attribute__((ext_vector_type(4))) float f32x4;

#define MFMA(a, b, c) __builtin_amdgcn_mfma_f32_16x16x32_bf16((a), (b), (c), 0, 0, 0)

__device__ __forceinline__ unsigned short f2bf(float f) {
    union { float f; unsigned u; } v; v.f = f;
    unsigned r = v.u + 0x7FFFu + ((v.u >> 16) & 1u);   // RNE
    return (unsigned short)(r >> 16);
}
__device__ __forceinline__ unsigned pack2(float lo, float hi) {
    return (unsigned)f2bf(lo) | ((unsigned)f2bf(hi) << 16);
}
__device__ __forceinline__ short8 ld8(const void* p) {
    return *reinterpret_cast<const short8*>(p);
}

// ---------------- kernel 0: cast weights to bf16 ----------------
__global__ __launch_bounds__(256) void k_prep(
    const float* __restrict__ wf, const float* __restrict__ wg,
    const float* __restrict__ wh, const float* __restrict__ wv,
    unsigned short* __restrict__ Wc, unsigned short* __restrict__ Wv)
{
    int i = blockIdx.x * 256 + threadIdx.x;
    if (i < MR_N * C_N) {
        int r = i / C_N, c = i % C_N;
        float v = (r < 32) ? wf[r * C_N + c]
                : (r < 64) ? wg[(r - 32) * C_N + c]
                           : wh[(r - 64) * C_N + c];
        Wc[i] = f2bf(v);
    }
    if (i < C_N * CH_N) Wv[i] = f2bf(wv[i]);
}

// ---------------- kernel 1: fused conv1x1 (f,g,h) + 2x2 maxpool ----------------
// Block: one batch, one (pooled-row, half) segment = 64 px (two 32-wide half-rows).
// Grid 1024. LDS: x tile as bf16 [64 px][256 ch], XOR-swizzled 16B chunks.
__global__ __launch_bounds__(256) void k_conv_fgh(
    const float* __restrict__ x, const unsigned short* __restrict__ Wc,
    const float* __restrict__ bfp, const float* __restrict__ bgp, const float* __restrict__ bhp,
    unsigned short* __restrict__ f_, unsigned short* __restrict__ g_, unsigned short* __restrict__ h_)
{
    __shared__ __align__(16) unsigned char lds[64 * 512];
    const int T = threadIdx.x;
    const int lane = T & 63, wid = T >> 6;
    const int blk = blockIdx.x;
    const int b = blk >> 6;
    const int seg = blk & 63;
    const int rp = seg >> 1;     // pooled row 0..31
    const int half = seg & 1;    // which 32-wide half of the row pair
    const float* xb = x + (size_t)b * C_N * HW_N;

    // stage x -> LDS bf16 (transpose to [px][ch] with chunk-XOR swizzle)
    #pragma unroll
    for (int i = 0; i < 8; ++i) {
        int task = i * 256 + T;        // 0..2047 = 16 px-quads x 128 ch-pairs
        int pq = task & 15;
        int cp = task >> 4;            // channel pair 0..127
        int px0 = pq * 4;
        int row = 2 * rp + (px0 >> 5);
        int wcol = half * 32 + (px0 & 31);
        const float4 v0 = *reinterpret_cast<const float4*>(xb + (size_t)(2 * cp) * HW_N + row * W_N + wcol);
        const float4 v1 = *reinterpret_cast<const float4*>(xb + (size_t)(2 * cp + 1) * HW_N + row * W_N + wcol);
        float vlo[4] = {v0.x, v0.y, v0.z, v0.w};
        float vhi[4] = {v1.x, v1.y, v1.z, v1.w};
        int kc = cp >> 2, co = cp & 3;
        #pragma unroll
        for (int j = 0; j < 4; ++j) {
            int px = px0 + j;
            *reinterpret_cast<unsigned*>(lds + px * 512 + ((kc ^ (px & 31)) << 4) + co * 4)
                = pack2(vlo[j], vhi[j]);
        }
    }
    __syncthreads();

    const int l15 = lane & 15, quad = lane >> 4;
    f32x4 acc[3][4];
    #pragma unroll
    for (int mt = 0; mt < 3; ++mt)
        #pragma unroll
        for (int nt = 0; nt < 4; ++nt)
            acc[mt][nt] = f32x4{0.f, 0.f, 0.f, 0.f};

    const int m0base = wid * 48;
    for (int k0 = 0; k0 < 256; k0 += 32) {
        short8 afr[3];
        #pragma unroll
        for (int mt = 0; mt < 3; ++mt)
            afr[mt] = ld8(Wc + (size_t)(m0base + mt * 16 + l15) * C_N + k0 + quad * 8);
        #pragma unroll
        for (int nt = 0; nt < 4; ++nt) {
            int px = nt * 16 + l15;
            int kc = (k0 >> 3) + quad;
            short8 bfr = ld8(lds + px * 512 + ((kc ^ (px & 31)) << 4));
            #pragma unroll
            for (int mt = 0; mt < 3; ++mt)
                acc[mt][nt] = MFMA(afr[mt], bfr, acc[mt][nt]);
        }
    }

    // epilogue: bias, pool, scatter to f/g/h
    #pragma unroll
    for (int mt = 0; mt < 3; ++mt) {
        int mbase = m0base + mt * 16;
        int mrow0 = mbase + quad * 4;
        float bias[4];
        #pragma unroll
        for (int r = 0; r < 4; ++r) {
            int m = mrow0 + r;
            bias[r] = (m < 32) ? bfp[m] : (m < 64) ? bgp[m - 32] : bhp[m - 64];
        }
        if (mbase < 32) {
            #pragma unroll
            for (int nt = 0; nt < 4; ++nt) {
                int px = nt * 16 + l15;
                int p = (2 * rp + (px >> 5)) * W_N + half * 32 + (px & 31);
                uint2 u;
                u.x = pack2(acc[mt][nt][0] + bias[0], acc[mt][nt][1] + bias[1]);
                u.y = pack2(acc[mt][nt][2] + bias[2], acc[mt][nt][3] + bias[3]);
                *reinterpret_cast<uint2*>(f_ + ((size_t)b * HW_N + p) * CK_N + mrow0) = u;
            }
        } else if (mbase < 64) {
            int gc0 = mrow0 - 32;
            #pragma unroll
            for (int nt = 0; nt < 2; ++nt) {
                float pv[4];
                #pragma unroll
                for (int r = 0; r < 4; ++r) {
                    float m1 = fmaxf(acc[mt][nt][r], acc[mt][nt + 2][r]);
                    pv[r] = fmaxf(m1, __shfl_xor(m1, 1)) + bias[r];
                }
                if ((lane & 1) == 0) {
                    int kp = rp * 32 + half * 16 + ((nt * 16 + l15) >> 1);
                    uint2 u;
                    u.x = pack2(pv[0], pv[1]);
                    u.y = pack2(pv[2], pv[3]);
                    *reinterpret_cast<uint2*>(g_ + ((size_t)b * HWP_N + kp) * CK_N + gc0) = u;
                }
            }
        } else {
            int hc0 = mrow0 - 64;
            #pragma unroll
            for (int nt = 0; nt < 2; ++nt) {
                float pv[4];
                #pragma unroll
                for (int r = 0; r < 4; ++r) {
                    float m1 = fmaxf(acc[mt][nt][r], acc[mt][nt + 2][r]);
                    pv[r] = fmaxf(m1, __shfl_xor(m1, 1)) + bias[r];
                }
                if ((lane & 1) == 0) {
                    int kp = rp * 32 + half * 16 + ((nt * 16 + l15) >> 1);
                    #pragma unroll
                    for (int r = 0; r < 4; ++r)
                        h_[((size_t)b * CH_N + hc0 + r) * HWP_N + kp] = f2bf(pv[r]);
                }
            }
        }
    }
}

// ---------------- kernel 2: fused attention (no s materialization) ----------------
// Block: one batch, 128 queries (4 waves x 32). Loop over 16 chunks of 64 keys.
// Q (f frags) in regs; g,V chunks staged in LDS; P round-trips per-wave LDS.
// No online max: fixed logit shift, fp32 accumulation, divide by sum at end.
__global__ __launch_bounds__(256) void k_attn(
    const unsigned short* __restrict__ f_, const unsigned short* __restrict__ g_,
    const unsigned short* __restrict__ h_, unsigned short* __restrict__ o_)
{
    __shared__ __align__(16) unsigned char lds[18432 + 5120 + 4 * 4608];
    unsigned char* Vl = lds;                 // [128 ch][144B] (64 keys + pad)
    unsigned char* Gl = lds + 18432;         // [64 keys][80B] (32 ch + pad)
    const int T = threadIdx.x;
    const int lane = T & 63, wid = T >> 6;
    unsigned char* Pl = lds + 18432 + 5120 + wid * 4608;  // per-wave [32 q][144B]
    const int l15 = lane & 15, quad = lane >> 4;

    const int blk = blockIdx.x;              // 512 = 16 b x 32 qtiles
    const int b = blk >> 5;
    const int q0w = (blk & 31) * 128 + wid * 32;
    const unsigned short* fb = f_ + (size_t)b * HW_N * CK_N;
    const unsigned short* gb = g_ + (size_t)b * HWP_N * CK_N;
    const unsigned short* hb = h_ + (size_t)b * CH_N * HWP_N;

    short8 ffr[2];
    #pragma unroll
    for (int qt = 0; qt < 2; ++qt)
        ffr[qt] = ld8(fb + (size_t)(q0w + qt * 16 + l15) * CK_N + quad * 8);

    f32x4 oacc[2][8];
    #pragma unroll
    for (int qt = 0; qt < 2; ++qt)
        #pragma unroll
        for (int ct = 0; ct < 8; ++ct)
            oacc[qt][ct] = f32x4{0.f, 0.f, 0.f, 0.f};
    float lsum[2] = {0.f, 0.f};
    const f32x4 zf = {0.f, 0.f, 0.f, 0.f};

    for (int key0 = 0; key0 < HWP_N; key0 += 64) {
        __syncthreads();  // previous chunk's LDS reads done
        #pragma unroll
        for (int i = 0; i < 4; ++i) {          // stage V chunk: 128ch x 64keys
            int task = i * 256 + T;
            int ch = task >> 3, kq = task & 7;
            short8 v = ld8(hb + (size_t)ch * HWP_N + key0 + kq * 8);
            *reinterpret_cast<short8*>(Vl + ch * 144 + kq * 16) = v;
        }
        {                                       // stage g chunk: 64keys x 32ch
            int key = T >> 2, cq = T & 3;
            short8 v = ld8(gb + (size_t)(key0 + key) * CK_N + cq * 8);
            *reinterpret_cast<short8*>(Gl + key * 80 + cq * 16) = v;
        }
        __syncthreads();

        // s^T tiles: rows=keys, cols=queries (K=32 -> one MFMA each)
        f32x4 sp[2][4];
        #pragma unroll
        for (int kt = 0; kt < 4; ++kt) {
            short8 gfr = ld8(Gl + (kt * 16 + l15) * 80 + quad * 16);
            #pragma unroll
            for (int qt = 0; qt < 2; ++qt)
                sp[qt][kt] = MFMA(gfr, ffr[qt], zf);
        }
        // exp (shifted), accumulate denominator, write P to per-wave LDS
        #pragma unroll
        for (int qt = 0; qt < 2; ++qt) {
            float lw = 0.f;
            #pragma unroll
            for (int kt = 0; kt < 4; ++kt) {
                float p[4];
                #pragma unroll
                for (int r = 0; r < 4; ++r) {
                    p[r] = __builtin_amdgcn_exp2f(sp[qt][kt][r] * 1.44269504f - 28.85390082f);
                    lw += p[r];
                }
                uint2 u;
                u.x = pack2(p[0], p[1]);
                u.y = pack2(p[2], p[3]);
                *reinterpret_cast<uint2*>(Pl + (qt * 16 + l15) * 144 + kt * 32 + quad * 8) = u;
            }
            lsum[qt] += lw;
        }
        // PV: o[q][ch] += P @ V  (per-wave P buffer, same-wave LDS ordering)
        #pragma unroll
        for (int s2 = 0; s2 < 2; ++s2) {
            short8 pfr0 = ld8(Pl + l15 * 144 + s2 * 64 + quad * 16);
            short8 pfr1 = ld8(Pl + (16 + l15) * 144 + s2 * 64 + quad * 16);
            #pragma unroll
            for (int ct = 0; ct < 8; ++ct) {
                short8 vfr = ld8(Vl + (ct * 16 + l15) * 144 + s2 * 64 + quad * 16);
                oacc[0][ct] = MFMA(pfr0, vfr, oacc[0][ct]);
                oacc[1][ct] = MFMA(pfr1, vfr, oacc[1][ct]);
            }
        }
    }

    // finalize: full denominator (cross-quad), scale, store o as [q][128ch] bf16
    lsum[0] += __shfl_xor(lsum[0], 16); lsum[0] += __shfl_xor(lsum[0], 32);
    lsum[1] += __shfl_xor(lsum[1], 16); lsum[1] += __shfl_xor(lsum[1], 32);
    float rl[2] = {1.f / lsum[0], 1.f / lsum[1]};
    unsigned short* ob = o_ + (size_t)b * HW_N * CH_N;
    #pragma unroll
    for (int qt = 0; qt < 2; ++qt) {
        float ss[4];
        #pragma unroll
        for (int r = 0; r < 4; ++r)
            ss[r] = __shfl(rl[qt], quad * 4 + r);
        #pragma unroll
        for (int ct = 0; ct < 8; ++ct) {
            int ch = ct * 16 + l15;
            #pragma unroll
            for (int r = 0; r < 4; ++r) {
                int q = q0w + qt * 16 + quad * 4 + r;
                ob[(size_t)q * CH_N + ch] = f2bf(oacc[qt][ct][r] * ss[r]);
            }
        }
    }
}

// ---------------- kernel 3: final conv1x1 + gamma + residual ----------------
// Block: one batch, 64 px, all 256 out channels (4 waves x 4 M-tiles). Grid 1024.
__global__ __launch_bounds__(256) void k_out(
    const unsigned short* __restrict__ o_, const unsigned short* __restrict__ Wv,
    const float* __restrict__ bv, const float* __restrict__ x,
    const float* __restrict__ gamma_p, float* __restrict__ out)
{
    __shared__ __align__(16) unsigned char lds[64 * 272];
    const int T = threadIdx.x;
    const int lane = T & 63, wid = T >> 6;
    const int blk = blockIdx.x;
    const int b = blk >> 6;
    const int p0 = (blk & 63) * 64;
    const unsigned short* ob = o_ + ((size_t)b * HW_N + p0) * CH_N;

    #pragma unroll
    for (int i = 0; i < 4; ++i) {      // stage o tile: 64px x 128ch, padded rows
        int task = i * 256 + T;
        int p = task >> 4, kc = task & 15;
        short8 v = ld8(ob + p * CH_N + kc * 8);
        *reinterpret_cast<short8*>(lds + p * 272 + kc * 16) = v;
    }
    __syncthreads();

    const int l15 = lane & 15, quad = lane >> 4;
    f32x4 acc[4][4];
    #pragma unroll
    for (int mt = 0; mt < 4; ++mt)
        #pragma unroll
        for (int nt = 0; nt < 4; ++nt)
            acc[mt][nt] = f32x4{0.f, 0.f, 0.f, 0.f};

    const int m0b = wid * 64;
    #pragma unroll
    for (int k0 = 0; k0 < 128; k0 += 32) {
        short8 bfr[4];
        #pragma unroll
        for (int nt = 0; nt < 4; ++nt)
            bfr[nt] = ld8(lds + (nt * 16 + l15) * 272 + k0 * 2 + quad * 16);
        #pragma unroll
        for (int mt = 0; mt < 4; ++mt) {
            short8 afr = ld8(Wv + (size_t)(m0b + mt * 16 + l15) * CH_N + k0 + quad * 8);
            #pragma unroll
            for (int nt = 0; nt < 4; ++nt)
                acc[mt][nt] = MFMA(afr, bfr[nt], acc[mt][nt]);
        }
    }

    const float gamma = *gamma_p;
    const float* xb = x + (size_t)b * C_N * HW_N;
    float* outb = out + (size_t)b * C_N * HW_N;
    #pragma unroll
    for (int mt = 0; mt < 4; ++mt) {
        int oc0 = m0b + mt * 16 + quad * 4;
        float bvv[4];
        #pragma unroll
        for (int r = 0; r < 4; ++r) bvv[r] = bv[oc0 + r];
        #pragma unroll
        for (int nt = 0; nt < 4; ++nt) {
            int p = p0 + nt * 16 + l15;
            #pragma unroll
            for (int r = 0; r < 4; ++r) {
                size_t idx = (size_t)(oc0 + r) * HW_N + p;
                outb[idx] = gamma * (acc[mt][nt][r] + bvv[r]) + xb[idx];
            }
        }
    }
}

// ---------------- launch ----------------
extern "C" void kernel_launch(void* const* d_in, const int* in_sizes, int n_in,
                              void* d_out, int out_size, void* d_ws, size_t ws_size,
                              hipStream_t stream) {
    const float* x     = (const float*)d_in[0];
    const float* wf    = (const float*)d_in[1];
    const float* bf    = (const float*)d_in[2];
    const float* wg    = (const float*)d_in[3];
    const float* bg    = (const float*)d_in[4];
    const float* wh    = (const float*)d_in[5];
    const float* bh    = (const float*)d_in[6];
    const float* wv    = (const float*)d_in[7];
    const float* bv    = (const float*)d_in[8];
    const float* gamma = (const float*)d_in[9];
    float* out = (float*)d_out;
    char* ws = (char*)d_ws;

    unsigned short* f_ = (unsigned short*)(ws);                 //  4,194,304 B
    unsigned short* g_ = (unsigned short*)(ws + 4194304);       //  1,048,576 B
    unsigned short* h_ = (unsigned short*)(ws + 5242880);       //  4,194,304 B
    unsigned short* o_ = (unsigned short*)(ws + 9437184);       // 16,777,216 B
    unsigned short* Wc = (unsigned short*)(ws + 26214400);      //     98,304 B
    unsigned short* Wv = (unsigned short*)(ws + 26312704);      //     65,536 B

    k_prep<<<192, 256, 0, stream>>>(wf, wg, wh, wv, Wc, Wv);
    k_conv_fgh<<<1024, 256, 0, stream>>>(x, Wc, bf, bg, bh, f_, g_, h_);
    k_attn<<<512, 256, 0, stream>>>(f_, g_, h_, o_);
    k_out<<<1024, 256, 0, stream>>>(o_, Wv, bv, x, gamma, out);
}

// Round 2
// 213.665 us; speedup vs baseline: 1.0466x; 1.0466x over previous
//
#include <hip/hip_runtime.h>
#include <hip/hip_bf16.h>
#include <stdint.h>

#define B_N   16
#define C_N   256
#define W_N   64
#define HW_N  4096
#define CK_N  32      // f,g channels
#define CH_N  128     // h channels
#define HWP_N 1024    // pooled spatial
#define MR_N  192     // CK+CK+CH rows in fused conv weight

typedef __attribute__((ext_vector_type(8))) short short8;
typedef __attribute__((ext_vector_type(4))) float f32x4;

#define MFMA(a, b, c) __builtin_amdgcn_mfma_f32_16x16x32_bf16((a), (b), (c), 0, 0, 0)

__device__ __forceinline__ unsigned short f2bf(float f) {
    union { float f; unsigned u; } v; v.f = f;
    unsigned r = v.u + 0x7FFFu + ((v.u >> 16) & 1u);   // RNE
    return (unsigned short)(r >> 16);
}
__device__ __forceinline__ unsigned pack2(float lo, float hi) {
    return (unsigned)f2bf(lo) | ((unsigned)f2bf(hi) << 16);
}
__device__ __forceinline__ short8 ld8(const void* p) {
    return *reinterpret_cast<const short8*>(p);
}

// ---------------- kernel 0: cast weights to bf16 ----------------
__global__ __launch_bounds__(256) void k_prep(
    const float* __restrict__ wf, const float* __restrict__ wg,
    const float* __restrict__ wh, const float* __restrict__ wv,
    unsigned short* __restrict__ Wc, unsigned short* __restrict__ Wv)
{
    int i = blockIdx.x * 256 + threadIdx.x;
    if (i < MR_N * C_N) {
        int r = i / C_N, c = i % C_N;
        float v = (r < 32) ? wf[r * C_N + c]
                : (r < 64) ? wg[(r - 32) * C_N + c]
                           : wh[(r - 64) * C_N + c];
        Wc[i] = f2bf(v);
    }
    if (i < C_N * CH_N) Wv[i] = f2bf(wv[i]);
}

// ---------------- kernel 1: fused conv1x1 (f,g,h) + 2x2 maxpool ----------------
// Block: one batch, one (pooled-row, half) segment = 64 px (two 32-wide half-rows).
// Grid 1024. LDS: x tile as bf16 [64 px][256 ch], XOR-swizzled 16B chunks.
__global__ __launch_bounds__(256) void k_conv_fgh(
    const float* __restrict__ x, const unsigned short* __restrict__ Wc,
    const float* __restrict__ bfp, const float* __restrict__ bgp, const float* __restrict__ bhp,
    unsigned short* __restrict__ f_, unsigned short* __restrict__ g_, unsigned short* __restrict__ h_)
{
    __shared__ __align__(16) unsigned char lds[64 * 512];
    const int T = threadIdx.x;
    const int lane = T & 63, wid = T >> 6;
    const int blk = blockIdx.x;
    const int b = blk >> 6;
    const int seg = blk & 63;
    const int rp = seg >> 1;     // pooled row 0..31
    const int half = seg & 1;    // which 32-wide half of the row pair
    const float* xb = x + (size_t)b * C_N * HW_N;

    // stage x -> LDS bf16 (transpose to [px][ch] with chunk-XOR swizzle)
    #pragma unroll
    for (int i = 0; i < 8; ++i) {
        int task = i * 256 + T;        // 0..2047 = 16 px-quads x 128 ch-pairs
        int pq = task & 15;
        int cp = task >> 4;            // channel pair 0..127
        int px0 = pq * 4;
        int row = 2 * rp + (px0 >> 5);
        int wcol = half * 32 + (px0 & 31);
        const float4 v0 = *reinterpret_cast<const float4*>(xb + (size_t)(2 * cp) * HW_N + row * W_N + wcol);
        const float4 v1 = *reinterpret_cast<const float4*>(xb + (size_t)(2 * cp + 1) * HW_N + row * W_N + wcol);
        float vlo[4] = {v0.x, v0.y, v0.z, v0.w};
        float vhi[4] = {v1.x, v1.y, v1.z, v1.w};
        int kc = cp >> 2, co = cp & 3;
        #pragma unroll
        for (int j = 0; j < 4; ++j) {
            int px = px0 + j;
            *reinterpret_cast<unsigned*>(lds + px * 512 + ((kc ^ (px & 31)) << 4) + co * 4)
                = pack2(vlo[j], vhi[j]);
        }
    }
    __syncthreads();

    const int l15 = lane & 15, quad = lane >> 4;
    f32x4 acc[3][4];
    #pragma unroll
    for (int mt = 0; mt < 3; ++mt)
        #pragma unroll
        for (int nt = 0; nt < 4; ++nt)
            acc[mt][nt] = f32x4{0.f, 0.f, 0.f, 0.f};

    const int m0base = wid * 48;
    for (int k0 = 0; k0 < 256; k0 += 32) {
        short8 afr[3];
        #pragma unroll
        for (int mt = 0; mt < 3; ++mt)
            afr[mt] = ld8(Wc + (size_t)(m0base + mt * 16 + l15) * C_N + k0 + quad * 8);
        #pragma unroll
        for (int nt = 0; nt < 4; ++nt) {
            int px = nt * 16 + l15;
            int kc = (k0 >> 3) + quad;
            short8 bfr = ld8(lds + px * 512 + ((kc ^ (px & 31)) << 4));
            #pragma unroll
            for (int mt = 0; mt < 3; ++mt)
                acc[mt][nt] = MFMA(afr[mt], bfr, acc[mt][nt]);
        }
    }

    // epilogue: bias, pool, scatter to f/g/h
    #pragma unroll
    for (int mt = 0; mt < 3; ++mt) {
        int mbase = m0base + mt * 16;
        int mrow0 = mbase + quad * 4;
        float bias[4];
        #pragma unroll
        for (int r = 0; r < 4; ++r) {
            int m = mrow0 + r;
            bias[r] = (m < 32) ? bfp[m] : (m < 64) ? bgp[m - 32] : bhp[m - 64];
        }
        if (mbase < 32) {
            #pragma unroll
            for (int nt = 0; nt < 4; ++nt) {
                int px = nt * 16 + l15;
                int p = (2 * rp + (px >> 5)) * W_N + half * 32 + (px & 31);
                uint2 u;
                u.x = pack2(acc[mt][nt][0] + bias[0], acc[mt][nt][1] + bias[1]);
                u.y = pack2(acc[mt][nt][2] + bias[2], acc[mt][nt][3] + bias[3]);
                *reinterpret_cast<uint2*>(f_ + ((size_t)b * HW_N + p) * CK_N + mrow0) = u;
            }
        } else if (mbase < 64) {
            int gc0 = mrow0 - 32;
            #pragma unroll
            for (int nt = 0; nt < 2; ++nt) {
                float pv[4];
                #pragma unroll
                for (int r = 0; r < 4; ++r) {
                    float m1 = fmaxf(acc[mt][nt][r], acc[mt][nt + 2][r]);
                    pv[r] = fmaxf(m1, __shfl_xor(m1, 1)) + bias[r];
                }
                if ((lane & 1) == 0) {
                    int kp = rp * 32 + half * 16 + ((nt * 16 + l15) >> 1);
                    uint2 u;
                    u.x = pack2(pv[0], pv[1]);
                    u.y = pack2(pv[2], pv[3]);
                    *reinterpret_cast<uint2*>(g_ + ((size_t)b * HWP_N + kp) * CK_N + gc0) = u;
                }
            }
        } else {
            int hc0 = mrow0 - 64;
            #pragma unroll
            for (int nt = 0; nt < 2; ++nt) {
                float pv[4];
                #pragma unroll
                for (int r = 0; r < 4; ++r) {
                    float m1 = fmaxf(acc[mt][nt][r], acc[mt][nt + 2][r]);
                    pv[r] = fmaxf(m1, __shfl_xor(m1, 1)) + bias[r];
                }
                // pack two adjacent pooled keys (held by lane, lane+2) into one
                // 4-B store; active lanes l15 in {0,4,8,12} then cover a
                // contiguous 16 B per channel row.
                #pragma unroll
                for (int r = 0; r < 4; ++r) {
                    int lo = (int)f2bf(pv[r]);
                    int hi = __shfl_down(lo, 2);
                    if ((lane & 3) == 0) {
                        int kp2 = rp * 32 + half * 16 + nt * 8 + (l15 >> 1);
                        *reinterpret_cast<unsigned*>(
                            h_ + ((size_t)b * CH_N + hc0 + r) * HWP_N + kp2)
                            = (unsigned)lo | ((unsigned)hi << 16);
                    }
                }
            }
        }
    }
}

// ---------------- kernel 2: fused attention (no s materialization) ----------------
// Block: one batch, 128 queries (4 waves x 32). Loop over 16 chunks of 64 keys.
// Q (f frags) in regs; g,V chunks staged in LDS; P round-trips per-wave LDS.
// No online max: fixed logit shift, fp32 accumulation, divide by sum at end.
__global__ __launch_bounds__(256) void k_attn(
    const unsigned short* __restrict__ f_, const unsigned short* __restrict__ g_,
    const unsigned short* __restrict__ h_, unsigned short* __restrict__ o_)
{
    __shared__ __align__(16) unsigned char lds[18432 + 5120 + 4 * 4608];
    unsigned char* Vl = lds;                 // [128 ch][144B] (64 keys + pad)
    unsigned char* Gl = lds + 18432;         // [64 keys][80B] (32 ch + pad)
    const int T = threadIdx.x;
    const int lane = T & 63, wid = T >> 6;
    unsigned char* Pl = lds + 18432 + 5120 + wid * 4608;  // per-wave [32 q][144B]
    const int l15 = lane & 15, quad = lane >> 4;

    const int blk = blockIdx.x;              // 512 = 16 b x 32 qtiles
    const int b = blk >> 5;
    const int q0w = (blk & 31) * 128 + wid * 32;
    const unsigned short* fb = f_ + (size_t)b * HW_N * CK_N;
    const unsigned short* gb = g_ + (size_t)b * HWP_N * CK_N;
    const unsigned short* hb = h_ + (size_t)b * CH_N * HWP_N;

    short8 ffr[2];
    #pragma unroll
    for (int qt = 0; qt < 2; ++qt)
        ffr[qt] = ld8(fb + (size_t)(q0w + qt * 16 + l15) * CK_N + quad * 8);

    f32x4 oacc[2][8];
    #pragma unroll
    for (int qt = 0; qt < 2; ++qt)
        #pragma unroll
        for (int ct = 0; ct < 8; ++ct)
            oacc[qt][ct] = f32x4{0.f, 0.f, 0.f, 0.f};
    float lsum[2] = {0.f, 0.f};
    const f32x4 zf = {0.f, 0.f, 0.f, 0.f};

    for (int key0 = 0; key0 < HWP_N; key0 += 64) {
        __syncthreads();  // previous chunk's LDS reads done
        #pragma unroll
        for (int i = 0; i < 4; ++i) {          // stage V chunk: 128ch x 64keys
            int task = i * 256 + T;
            int ch = task >> 3, kq = task & 7;
            short8 v = ld8(hb + (size_t)ch * HWP_N + key0 + kq * 8);
            *reinterpret_cast<short8*>(Vl + ch * 144 + kq * 16) = v;
        }
        {                                       // stage g chunk: 64keys x 32ch
            int key = T >> 2, cq = T & 3;
            short8 v = ld8(gb + (size_t)(key0 + key) * CK_N + cq * 8);
            *reinterpret_cast<short8*>(Gl + key * 80 + cq * 16) = v;
        }
        __syncthreads();

        // s^T tiles: rows=keys, cols=queries (K=32 -> one MFMA each)
        f32x4 sp[2][4];
        #pragma unroll
        for (int kt = 0; kt < 4; ++kt) {
            short8 gfr = ld8(Gl + (kt * 16 + l15) * 80 + quad * 16);
            #pragma unroll
            for (int qt = 0; qt < 2; ++qt)
                sp[qt][kt] = MFMA(gfr, ffr[qt], zf);
        }
        // exp (shifted), accumulate denominator, write P to per-wave LDS
        #pragma unroll
        for (int qt = 0; qt < 2; ++qt) {
            float lw = 0.f;
            #pragma unroll
            for (int kt = 0; kt < 4; ++kt) {
                float p[4];
                #pragma unroll
                for (int r = 0; r < 4; ++r) {
                    p[r] = __builtin_amdgcn_exp2f(sp[qt][kt][r] * 1.44269504f - 28.85390082f);
                    lw += p[r];
                }
                uint2 u;
                u.x = pack2(p[0], p[1]);
                u.y = pack2(p[2], p[3]);
                *reinterpret_cast<uint2*>(Pl + (qt * 16 + l15) * 144 + kt * 32 + quad * 8) = u;
            }
            lsum[qt] += lw;
        }
        // PV: o[q][ch] += P @ V  (per-wave P buffer, same-wave LDS ordering)
        #pragma unroll
        for (int s2 = 0; s2 < 2; ++s2) {
            short8 pfr0 = ld8(Pl + l15 * 144 + s2 * 64 + quad * 16);
            short8 pfr1 = ld8(Pl + (16 + l15) * 144 + s2 * 64 + quad * 16);
            #pragma unroll
            for (int ct = 0; ct < 8; ++ct) {
                short8 vfr = ld8(Vl + (ct * 16 + l15) * 144 + s2 * 64 + quad * 16);
                oacc[0][ct] = MFMA(pfr0, vfr, oacc[0][ct]);
                oacc[1][ct] = MFMA(pfr1, vfr, oacc[1][ct]);
            }
        }
    }

    // finalize: full denominator (cross-quad), scale, store o as [q][128ch] bf16
    lsum[0] += __shfl_xor(lsum[0], 16); lsum[0] += __shfl_xor(lsum[0], 32);
    lsum[1] += __shfl_xor(lsum[1], 16); lsum[1] += __shfl_xor(lsum[1], 32);
    float rl[2] = {1.f / lsum[0], 1.f / lsum[1]};
    unsigned short* ob = o_ + (size_t)b * HW_N * CH_N;
    #pragma unroll
    for (int qt = 0; qt < 2; ++qt) {
        float ss[4];
        #pragma unroll
        for (int r = 0; r < 4; ++r)
            ss[r] = __shfl(rl[qt], quad * 4 + r);
        #pragma unroll
        for (int ct = 0; ct < 8; ++ct) {
            int ch = ct * 16 + l15;
            #pragma unroll
            for (int r = 0; r < 4; ++r) {
                int q = q0w + qt * 16 + quad * 4 + r;
                ob[(size_t)q * CH_N + ch] = f2bf(oacc[qt][ct][r] * ss[r]);
            }
        }
    }
}

// ---------------- kernel 3: final conv1x1 + gamma + residual ----------------
// Block: one batch, 64 px, all 256 out channels (4 waves x 4 M-tiles). Grid 1024.
// MFMA operand order: A = o-tile (m = px), B = Wv (n = oc), so each lane's 4
// accumulator regs are 4 CONSECUTIVE PIXELS of one channel -> float4 epilogue.
__global__ __launch_bounds__(256) void k_out(
    const unsigned short* __restrict__ o_, const unsigned short* __restrict__ Wv,
    const float* __restrict__ bv, const float* __restrict__ x,
    const float* __restrict__ gamma_p, float* __restrict__ out)
{
    __shared__ __align__(16) unsigned char lds[64 * 272];
    const int T = threadIdx.x;
    const int lane = T & 63, wid = T >> 6;
    const int blk = blockIdx.x;
    const int b = blk >> 6;
    const int p0 = (blk & 63) * 64;
    const unsigned short* ob = o_ + ((size_t)b * HW_N + p0) * CH_N;

    #pragma unroll
    for (int i = 0; i < 4; ++i) {      // stage o tile: 64px x 128ch, padded rows
        int task = i * 256 + T;
        int p = task >> 4, kc = task & 15;
        short8 v = ld8(ob + p * CH_N + kc * 8);
        *reinterpret_cast<short8*>(lds + p * 272 + kc * 16) = v;
    }
    __syncthreads();

    const int l15 = lane & 15, quad = lane >> 4;
    f32x4 acc[4][4];   // acc[oc-tile][px-tile]; D row=px(quad*4+r), col=oc(l15)
    #pragma unroll
    for (int mt = 0; mt < 4; ++mt)
        #pragma unroll
        for (int nt = 0; nt < 4; ++nt)
            acc[mt][nt] = f32x4{0.f, 0.f, 0.f, 0.f};

    const int m0b = wid * 64;
    #pragma unroll
    for (int k0 = 0; k0 < 128; k0 += 32) {
        short8 bfr[4];   // o-tile fragments, m = px (A operand)
        #pragma unroll
        for (int nt = 0; nt < 4; ++nt)
            bfr[nt] = ld8(lds + (nt * 16 + l15) * 272 + k0 * 2 + quad * 16);
        #pragma unroll
        for (int mt = 0; mt < 4; ++mt) {
            short8 afr = ld8(Wv + (size_t)(m0b + mt * 16 + l15) * CH_N + k0 + quad * 8);
            #pragma unroll
            for (int nt = 0; nt < 4; ++nt)
                acc[mt][nt] = MFMA(bfr[nt], afr, acc[mt][nt]);  // A=o(px), B=Wv(oc)
        }
    }

    const float gamma = *gamma_p;
    const float* xb = x + (size_t)b * C_N * HW_N;
    float* outb = out + (size_t)b * C_N * HW_N;
    #pragma unroll
    for (int mt = 0; mt < 4; ++mt) {
        int oc = m0b + mt * 16 + l15;
        float bvv = bv[oc];
        #pragma unroll
        for (int nt = 0; nt < 4; ++nt) {
            size_t base = (size_t)oc * HW_N + p0 + nt * 16 + quad * 4;
            float4 xv = *reinterpret_cast<const float4*>(xb + base);
            float4 ov;
            ov.x = gamma * (acc[mt][nt][0] + bvv) + xv.x;
            ov.y = gamma * (acc[mt][nt][1] + bvv) + xv.y;
            ov.z = gamma * (acc[mt][nt][2] + bvv) + xv.z;
            ov.w = gamma * (acc[mt][nt][3] + bvv) + xv.w;
            *reinterpret_cast<float4*>(outb + base) = ov;
        }
    }
}

// ---------------- launch ----------------
extern "C" void kernel_launch(void* const* d_in, const int* in_sizes, int n_in,
                              void* d_out, int out_size, void* d_ws, size_t ws_size,
                              hipStream_t stream) {
    const float* x     = (const float*)d_in[0];
    const float* wf    = (const float*)d_in[1];
    const float* bf    = (const float*)d_in[2];
    const float* wg    = (const float*)d_in[3];
    const float* bg    = (const float*)d_in[4];
    const float* wh    = (const float*)d_in[5];
    const float* bh    = (const float*)d_in[6];
    const float* wv    = (const float*)d_in[7];
    const float* bv    = (const float*)d_in[8];
    const float* gamma = (const float*)d_in[9];
    float* out = (float*)d_out;
    char* ws = (char*)d_ws;

    unsigned short* f_ = (unsigned short*)(ws);                 //  4,194,304 B
    unsigned short* g_ = (unsigned short*)(ws + 4194304);       //  1,048,576 B
    unsigned short* h_ = (unsigned short*)(ws + 5242880);       //  4,194,304 B
    unsigned short* o_ = (unsigned short*)(ws + 9437184);       // 16,777,216 B
    unsigned short* Wc = (unsigned short*)(ws + 26214400);      //     98,304 B
    unsigned short* Wv = (unsigned short*)(ws + 26312704);      //     65,536 B

    k_prep<<<192, 256, 0, stream>>>(wf, wg, wh, wv, Wc, Wv);
    k_conv_fgh<<<1024, 256, 0, stream>>>(x, Wc, bf, bg, bh, f_, g_, h_);
    k_attn<<<512, 256, 0, stream>>>(f_, g_, h_, o_);
    k_out<<<1024, 256, 0, stream>>>(o_, Wv, bv, x, gamma, out);
}